// Round 1
// baseline (142.493 us; speedup 1.0000x reference)
//
#include <hip/hip_runtime.h>
#include <math.h>

#define BATCH 8
#define NBOX 10000
#define NCLS 80
#define KSEL 8
#define MAXT 8
#define IOU_THR 0.5f
#define SCORE_THR 0.5f
#define NEGV -1000000000.0f

// Block-wide argmax with first-index tie-break (matches jnp.argmax).
// red_val/red_idx are 4-entry shared scratch. On return every thread holds
// the winning (best, bidx).
__device__ __forceinline__ void block_argmax(float& best, int& bidx,
                                             float* red_val, int* red_idx,
                                             int tid) {
    #pragma unroll
    for (int off = 32; off > 0; off >>= 1) {
        float ov = __shfl_down(best, off, 64);
        int   oi = __shfl_down(bidx, off, 64);
        if (ov > best || (ov == best && oi < bidx)) { best = ov; bidx = oi; }
    }
    int wave = tid >> 6;
    if ((tid & 63) == 0) { red_val[wave] = best; red_idx[wave] = bidx; }
    __syncthreads();
    if (tid == 0) {
        #pragma unroll
        for (int w = 1; w < 4; ++w) {
            float ov = red_val[w]; int oi = red_idx[w];
            if (ov > best || (ov == best && oi < bidx)) { best = ov; bidx = oi; }
        }
        red_val[0] = best; red_idx[0] = bidx;
    }
    __syncthreads();
    best = red_val[0]; bidx = red_idx[0];
    // NOTE: callers must have a barrier before red_* is written again
    // (the per-round __syncthreads in both kernels provides it).
}

// One block per (b, c): per-class NMS, K sequential argmax+suppress rounds.
__global__ __launch_bounds__(256) void nms_per_class(
    const float* __restrict__ boxes,    // (B, N, 4) fp32
    const float* __restrict__ scores,   // (B, N, C) fp32
    float* __restrict__ ws_msc,         // (B*C*K) masked scores
    float4* __restrict__ ws_box)        // (B*C*K) selected boxes (raw)
{
    __shared__ float s[NBOX];           // 40 KB masked score array
    __shared__ float red_val[4];
    __shared__ int   red_idx[4];

    const int bc  = blockIdx.x;
    const int b   = bc / NCLS;
    const int c   = bc % NCLS;
    const int tid = threadIdx.x;

    // Load + threshold scores for this (b, :, c). Stride NCLS floats.
    const float* sc_base = scores + (size_t)b * NBOX * NCLS + c;
    for (int n = tid; n < NBOX; n += 256) {
        float v = sc_base[(size_t)n * NCLS];
        s[n] = (v > SCORE_THR) ? v : NEGV;
    }
    __syncthreads();

    const float4* box_base =
        (const float4*)(boxes + (size_t)b * NBOX * 4);

    for (int k = 0; k < KSEL; ++k) {
        // ---- argmax over s (first-index tie-break) ----
        float best = -INFINITY;
        int   bidx = 0x7fffffff;
        for (int n = tid; n < NBOX; n += 256) {
            float v = s[n];
            if (v > best) { best = v; bidx = n; }   // ascending scan keeps first max
        }
        block_argmax(best, bidx, red_val, red_idx, tid);
        const int   sel = bidx;
        const float val = best;

        // Selected box (all lanes same address -> single broadcast load).
        const float4 sb = box_base[sel];

        if (tid == 0) {
            float msc = (val > SCORE_THR) ? val : NEGV;  // masked = valid? sc : NEG
            int o = bc * KSEL + k;                       // (b, c*K + k)
            ws_msc[o] = msc;
            ws_box[o] = sb;
        }

        // ---- IoU suppression (per-op IEEE rounding to match numpy exactly) ----
        const float y1 = sb.x, x1 = sb.y, y2 = sb.z, x2 = sb.w;
        const float area = __fmul_rn(__fsub_rn(y2, y1), __fsub_rn(x2, x1));
        for (int n = tid; n < NBOX; n += 256) {
            float4 bb = box_base[n];                 // Y1=bb.x X1=bb.y Y2=bb.z X2=bb.w
            float ih = fmaxf(__fsub_rn(fminf(y2, bb.z), fmaxf(y1, bb.x)), 0.0f);
            float iw = fmaxf(__fsub_rn(fminf(x2, bb.w), fmaxf(x1, bb.y)), 0.0f);
            float inter = __fmul_rn(ih, iw);
            float areas = __fmul_rn(__fsub_rn(bb.z, bb.x), __fsub_rn(bb.w, bb.y));
            float uni   = __fsub_rn(__fadd_rn(area, areas), inter);
            float iou   = __fdiv_rn(inter, fmaxf(uni, 1e-9f));
            // reference: s = where(iou>thr, NEG, s); s[idx] = NEG
            if (iou > IOU_THR || n == sel) s[n] = NEGV;
        }
        __syncthreads();
    }
}

// One block per batch: stable top-MAXT over C*K masked scores, write outputs.
__global__ __launch_bounds__(256) void topk_combine(
    const float* __restrict__ ws_msc,
    const float4* __restrict__ ws_box,
    float* __restrict__ out)
{
    __shared__ float v[NCLS * KSEL];    // 640
    __shared__ float red_val[4];
    __shared__ int   red_idx[4];
    __shared__ int   sel_i[MAXT];
    __shared__ float sel_v[MAXT];

    const int b = blockIdx.x;
    const int tid = threadIdx.x;

    for (int i = tid; i < NCLS * KSEL; i += 256)
        v[i] = ws_msc[b * NCLS * KSEL + i];
    __syncthreads();

    for (int t = 0; t < MAXT; ++t) {
        float best = -INFINITY;
        int   bidx = 0x7fffffff;
        for (int i = tid; i < NCLS * KSEL; i += 256) {
            float x = v[i];
            if (x > best || (x == best && i < bidx)) { best = x; bidx = i; }
        }
        block_argmax(best, bidx, red_val, red_idx, tid);
        if (tid == 0) {
            sel_i[t] = bidx;
            sel_v[t] = best;
            v[bidx] = -INFINITY;        // remove; below NEG so never re-picked
        }
        __syncthreads();
    }

    // d_out layout (flat fp32): boxes[B][MAXT][4] | scores[B][MAXT]
    //                         | classes[B][MAXT]  | valid_det[B]
    const int OFF_SC  = BATCH * MAXT * 4;       // 256
    const int OFF_CL  = OFF_SC + BATCH * MAXT;  // 320
    const int OFF_VD  = OFF_CL + BATCH * MAXT;  // 384

    if (tid < MAXT) {
        const int t = tid;
        const int idx = sel_i[t];
        const float val = sel_v[t];
        const bool valid = val > SCORE_THR;
        float4 bx = ws_box[b * NCLS * KSEL + idx];
        float* ob = out + ((size_t)b * MAXT + t) * 4;
        ob[0] = valid ? fminf(fmaxf(bx.x, 0.0f), 1.0f) : 0.0f;
        ob[1] = valid ? fminf(fmaxf(bx.y, 0.0f), 1.0f) : 0.0f;
        ob[2] = valid ? fminf(fmaxf(bx.z, 0.0f), 1.0f) : 0.0f;
        ob[3] = valid ? fminf(fmaxf(bx.w, 0.0f), 1.0f) : 0.0f;
        out[OFF_SC + b * MAXT + t] = valid ? val : 0.0f;
        out[OFF_CL + b * MAXT + t] = valid ? (float)(idx >> 3) : 0.0f; // idx/K -> class
    }
    if (tid == 0) {
        int cnt = 0;
        #pragma unroll
        for (int t = 0; t < MAXT; ++t) cnt += (sel_v[t] > SCORE_THR) ? 1 : 0;
        out[OFF_VD + b] = (float)cnt;
    }
}

extern "C" void kernel_launch(void* const* d_in, const int* in_sizes, int n_in,
                              void* d_out, int out_size, void* d_ws, size_t ws_size,
                              hipStream_t stream) {
    const float* boxes  = (const float*)d_in[0];   // (B, N, 1, 4)
    const float* scores = (const float*)d_in[1];   // (B, N, C)
    float* out = (float*)d_out;

    // Workspace layout: msc (B*C*K floats = 20480 B) | box (B*C*K float4 = 81920 B)
    float*  ws_msc = (float*)d_ws;
    float4* ws_box = (float4*)((char*)d_ws + BATCH * NCLS * KSEL * sizeof(float));

    nms_per_class<<<BATCH * NCLS, 256, 0, stream>>>(boxes, scores, ws_msc, ws_box);
    topk_combine<<<BATCH, 256, 0, stream>>>(ws_msc, ws_box, out);
}

// Round 2
// 68.766 us; speedup vs baseline: 2.0721x; 2.0721x over previous
//
#include <hip/hip_runtime.h>
#include <math.h>

#define BATCH 8
#define NBOX 10000
#define NCLS 80
#define KSEL 8
#define MAXT 8
#define IOU_THR 0.5f
#define SCORE_THR 0.5f
#define NEGV -1000000000.0f
#define NSEG 256
#define TILE_N 64

// Block-wide argmax with first-index tie-break (matches jnp.argmax).
__device__ __forceinline__ void block_argmax(float& best, int& bidx,
                                             float* red_val, int* red_idx,
                                             int tid) {
    #pragma unroll
    for (int off = 32; off > 0; off >>= 1) {
        float ov = __shfl_down(best, off, 64);
        int   oi = __shfl_down(bidx, off, 64);
        if (ov > best || (ov == best && oi < bidx)) { best = ov; bidx = oi; }
    }
    int wave = tid >> 6;
    if ((tid & 63) == 0) { red_val[wave] = best; red_idx[wave] = bidx; }
    __syncthreads();
    if (tid == 0) {
        #pragma unroll
        for (int w = 1; w < 4; ++w) {
            float ov = red_val[w]; int oi = red_idx[w];
            if (ov > best || (ov == best && oi < bidx)) { best = ov; bidx = oi; }
        }
        red_val[0] = best; red_idx[0] = bidx;
    }
    __syncthreads();
    best = red_val[0]; bidx = red_idx[0];
    // Callers must barrier before red_* is reused (round-end barriers do).
}

// Coalesced transpose + threshold: (B,N,C) -> (B*C, N), NEG where <= thr.
__global__ __launch_bounds__(256) void transpose_scores(
    const float* __restrict__ scores, float* __restrict__ st)
{
    __shared__ float tile[NCLS][TILE_N + 1];
    const int b   = blockIdx.y;
    const int n0  = blockIdx.x * TILE_N;
    const int tid = threadIdx.x;
    const int nrem = min(TILE_N, NBOX - n0);
    const float* src = scores + (size_t)b * NBOX * NCLS + (size_t)n0 * NCLS;
    for (int i = tid; i < nrem * NCLS; i += 256) {
        int nl = i / NCLS, c = i - nl * NCLS;
        float v = src[i];
        tile[c][nl] = (v > SCORE_THR) ? v : NEGV;
    }
    __syncthreads();
    for (int j = tid; j < NCLS * TILE_N; j += 256) {
        int c = j / TILE_N, nl = j - c * TILE_N;
        if (nl < nrem)
            st[((size_t)b * NCLS + c) * NBOX + n0 + nl] = tile[c][nl];
    }
}

// One block per (b,c): candidate extraction in score order with hierarchical
// argmax. Equivalent to reference greedy NMS: a candidate is kept iff it does
// not overlap (iou > thr) any previously-kept box.
__global__ __launch_bounds__(256) void nms_extract(
    const float* __restrict__ st,       // (B*C, N) thresholded, or nullptr
    const float* __restrict__ scores,   // raw (B,N,C) fallback
    const float* __restrict__ boxes,    // (B,N,4)
    float* __restrict__ ws_msc,
    float4* __restrict__ ws_box,
    int use_t)
{
    __shared__ float4 s4[NBOX / 4];     // 40 KB score array
    __shared__ float seg_val[NSEG];
    __shared__ int   seg_idx[NSEG];
    __shared__ float red_val[4];
    __shared__ int   red_idx[4];
    __shared__ float4 karr[MAXT];
    __shared__ float  karea[MAXT];
    float* s = (float*)s4;

    const int bc  = blockIdx.x;
    const int b   = bc / NCLS;
    const int tid = threadIdx.x;
    const float4* box_base = (const float4*)(boxes + (size_t)b * NBOX * 4);

    // ---- load scores (thresholded) into LDS ----
    if (use_t) {
        const float4* src = (const float4*)(st + (size_t)bc * NBOX);
        for (int i = tid; i < NBOX / 4; i += 256) s4[i] = src[i];
    } else {
        const int c = bc - b * NCLS;
        const float* base = scores + (size_t)b * NBOX * NCLS + c;
        for (int n = tid; n < NBOX; n += 256) {
            float v = base[(size_t)n * NCLS];
            s[n] = (v > SCORE_THR) ? v : NEGV;
        }
    }
    __syncthreads();

    // ---- per-segment maxima (strided ownership: thread t owns n ≡ t mod 256) ----
    {
        float mv = NEGV; int mi = tid;
        for (int idx = tid; idx < NBOX; idx += NSEG) {
            float v = s[idx];
            if (v > mv) { mv = v; mi = idx; }   // ascending scan -> first max
        }
        seg_val[tid] = mv; seg_idx[tid] = mi;
    }
    __syncthreads();

    // ---- extraction rounds ----
    int kept = 0;
    for (;;) {
        float bv = seg_val[tid]; int bi = seg_idx[tid];
        block_argmax(bv, bi, red_val, red_idx, tid);
        if (!(bv > SCORE_THR)) break;           // only NEG left

        const float4 cb = box_base[bi];         // broadcast load
        const float carea = __fmul_rn(__fsub_rn(cb.z, cb.x), __fsub_rn(cb.w, cb.y));

        // IoU vs previously-kept boxes (<= 8), per-op IEEE to match numpy
        bool sup = false;
        for (int j = 0; j < kept; ++j) {
            float4 kb = karr[j];
            float ih = fmaxf(__fsub_rn(fminf(kb.z, cb.z), fmaxf(kb.x, cb.x)), 0.0f);
            float iw = fmaxf(__fsub_rn(fminf(kb.w, cb.w), fmaxf(kb.y, cb.y)), 0.0f);
            float inter = __fmul_rn(ih, iw);
            float uni   = __fsub_rn(__fadd_rn(karea[j], carea), inter);
            float iou   = __fdiv_rn(inter, fmaxf(uni, 1e-9f));
            if (iou > IOU_THR) { sup = true; break; }
        }

        if (!sup) {
            if (tid == 0) {
                int o = bc * KSEL + kept;
                ws_msc[o]   = bv;
                ws_box[o]   = cb;
                karr[kept]  = cb;
                karea[kept] = carea;
            }
            kept++;
        }

        // remove candidate; rescan only its owner segment (<= 40 elements)
        const int owner = bi & (NSEG - 1);
        if (tid == owner) {
            s[bi] = NEGV;
            float mv = NEGV; int mi = owner;
            for (int idx = owner; idx < NBOX; idx += NSEG) {
                float v = s[idx];
                if (v > mv) { mv = v; mi = idx; }
            }
            seg_val[owner] = mv; seg_idx[owner] = mi;
        }
        __syncthreads();
        if (kept == MAXT) break;
    }

    if (tid == 0) {
        for (int k = kept; k < MAXT; ++k) {
            int o = bc * KSEL + k;
            ws_msc[o] = NEGV;
            ws_box[o] = make_float4(0.f, 0.f, 0.f, 0.f);
        }
    }
}

// One block per batch: stable top-MAXT over C*K masked scores, write outputs.
__global__ __launch_bounds__(256) void topk_combine(
    const float* __restrict__ ws_msc,
    const float4* __restrict__ ws_box,
    float* __restrict__ out)
{
    __shared__ float v[NCLS * KSEL];
    __shared__ float red_val[4];
    __shared__ int   red_idx[4];
    __shared__ int   sel_i[MAXT];
    __shared__ float sel_v[MAXT];

    const int b = blockIdx.x;
    const int tid = threadIdx.x;

    for (int i = tid; i < NCLS * KSEL; i += 256)
        v[i] = ws_msc[b * NCLS * KSEL + i];
    __syncthreads();

    for (int t = 0; t < MAXT; ++t) {
        float best = -INFINITY;
        int   bidx = 0x7fffffff;
        for (int i = tid; i < NCLS * KSEL; i += 256) {
            float x = v[i];
            if (x > best || (x == best && i < bidx)) { best = x; bidx = i; }
        }
        block_argmax(best, bidx, red_val, red_idx, tid);
        if (tid == 0) {
            sel_i[t] = bidx;
            sel_v[t] = best;
            v[bidx] = -INFINITY;
        }
        __syncthreads();
    }

    const int OFF_SC = BATCH * MAXT * 4;
    const int OFF_CL = OFF_SC + BATCH * MAXT;
    const int OFF_VD = OFF_CL + BATCH * MAXT;

    if (tid < MAXT) {
        const int t = tid;
        const int idx = sel_i[t];
        const float val = sel_v[t];
        const bool valid = val > SCORE_THR;
        float4 bx = ws_box[b * NCLS * KSEL + idx];
        float* ob = out + ((size_t)b * MAXT + t) * 4;
        ob[0] = valid ? fminf(fmaxf(bx.x, 0.0f), 1.0f) : 0.0f;
        ob[1] = valid ? fminf(fmaxf(bx.y, 0.0f), 1.0f) : 0.0f;
        ob[2] = valid ? fminf(fmaxf(bx.z, 0.0f), 1.0f) : 0.0f;
        ob[3] = valid ? fminf(fmaxf(bx.w, 0.0f), 1.0f) : 0.0f;
        out[OFF_SC + b * MAXT + t] = valid ? val : 0.0f;
        out[OFF_CL + b * MAXT + t] = valid ? (float)(idx >> 3) : 0.0f;
    }
    if (tid == 0) {
        int cnt = 0;
        #pragma unroll
        for (int t = 0; t < MAXT; ++t) cnt += (sel_v[t] > SCORE_THR) ? 1 : 0;
        out[OFF_VD + b] = (float)cnt;
    }
}

extern "C" void kernel_launch(void* const* d_in, const int* in_sizes, int n_in,
                              void* d_out, int out_size, void* d_ws, size_t ws_size,
                              hipStream_t stream) {
    const float* boxes  = (const float*)d_in[0];   // (B, N, 1, 4)
    const float* scores = (const float*)d_in[1];   // (B, N, C)
    float* out = (float*)d_out;

    const size_t t_bytes   = (size_t)BATCH * NCLS * NBOX * sizeof(float); // 25.6 MB
    const size_t msc_bytes = (size_t)BATCH * NCLS * KSEL * sizeof(float); // 20 KB
    const size_t box_bytes = (size_t)BATCH * NCLS * KSEL * sizeof(float4);// 80 KB

    int use_t = (ws_size >= t_bytes + msc_bytes + box_bytes) ? 1 : 0;

    float* st; float* ws_msc; float4* ws_box;
    if (use_t) {
        st     = (float*)d_ws;
        ws_msc = (float*)((char*)d_ws + t_bytes);
        ws_box = (float4*)((char*)d_ws + t_bytes + msc_bytes);
    } else {
        st     = nullptr;
        ws_msc = (float*)d_ws;
        ws_box = (float4*)((char*)d_ws + msc_bytes);
    }

    if (use_t) {
        dim3 tg((NBOX + TILE_N - 1) / TILE_N, BATCH);
        transpose_scores<<<tg, 256, 0, stream>>>(scores, st);
    }
    nms_extract<<<BATCH * NCLS, 256, 0, stream>>>(st, scores, boxes, ws_msc, ws_box, use_t);
    topk_combine<<<BATCH, 256, 0, stream>>>(ws_msc, ws_box, out);
}

// Round 3
// 57.964 us; speedup vs baseline: 2.4583x; 1.1864x over previous
//
#include <hip/hip_runtime.h>
#include <math.h>

#define BATCH 8
#define NBOX 10000
#define NCLS 80
#define KSEL 8
#define MAXT 8
#define IOU_THR 0.5f
#define SCORE_THR 0.5f
#define NEGV -1000000000.0f
#define VPT 40              // values per thread: 256 * 40 = 10240 >= 10000
#define TILE_N 64

// Block-wide argmax with first-index tie-break (matches jnp.argmax).
// red_* are 4-entry wave-partial slots; bcast_* is a separate broadcast slot
// so cross-round reuse needs no extra barrier (2 barriers per call total).
__device__ __forceinline__ void block_argmax(float& best, int& bidx,
                                             float* red_val, int* red_idx,
                                             float* bcast_val, int* bcast_idx,
                                             int tid) {
    #pragma unroll
    for (int off = 32; off > 0; off >>= 1) {
        float ov = __shfl_down(best, off, 64);
        int   oi = __shfl_down(bidx, off, 64);
        if (ov > best || (ov == best && oi < bidx)) { best = ov; bidx = oi; }
    }
    int wave = tid >> 6;
    if ((tid & 63) == 0) { red_val[wave] = best; red_idx[wave] = bidx; }
    __syncthreads();                       // (A)
    if (tid == 0) {
        #pragma unroll
        for (int w = 1; w < 4; ++w) {
            float ov = red_val[w]; int oi = red_idx[w];
            if (ov > best || (ov == best && oi < bidx)) { best = ov; bidx = oi; }
        }
        bcast_val[0] = best; bcast_idx[0] = bidx;
    }
    __syncthreads();                       // (B)
    best = bcast_val[0]; bidx = bcast_idx[0];
}

// Coalesced vectorized transpose + threshold: (B,N,C) -> (B*C, N).
__global__ __launch_bounds__(256) void transpose_scores(
    const float* __restrict__ scores, float* __restrict__ st)
{
    __shared__ float tile[TILE_N][NCLS + 4];   // stride 84: rows 16B-aligned, 21.5 KB
    const int b   = blockIdx.y;
    const int n0  = blockIdx.x * TILE_N;
    const int tid = threadIdx.x;
    const int nrem = min(TILE_N, NBOX - n0);   // 64, or 16 for the last block
    const float4* src = (const float4*)(scores + (size_t)b * NBOX * NCLS
                                               + (size_t)n0 * NCLS);
    if (nrem == TILE_N) {
        // load: 64*80/4 = 1280 float4, 5 per thread
        #pragma unroll
        for (int k = 0; k < 5; ++k) {
            int i = tid + k * 256;
            float4 v = src[i];
            int nl = i / 20, c4 = i - nl * 20;
            float4 o;
            o.x = (v.x > SCORE_THR) ? v.x : NEGV;
            o.y = (v.y > SCORE_THR) ? v.y : NEGV;
            o.z = (v.z > SCORE_THR) ? v.z : NEGV;
            o.w = (v.w > SCORE_THR) ? v.w : NEGV;
            *(float4*)&tile[nl][c4 * 4] = o;
        }
        __syncthreads();
        // store: per (n4, c): float4 over n = n0 + n4*4 + q at fixed class c.
        // lane-consecutive c -> conflict-free LDS reads + coalesced-ish stores
        #pragma unroll
        for (int k = 0; k < 5; ++k) {
            int j = tid + k * 256;          // j in [0, 16*80)
            int n4 = j / NCLS, c = j - n4 * NCLS;
            float4 o;
            o.x = tile[n4 * 4 + 0][c];
            o.y = tile[n4 * 4 + 1][c];
            o.z = tile[n4 * 4 + 2][c];
            o.w = tile[n4 * 4 + 3][c];
            *(float4*)&st[((size_t)b * NCLS + c) * NBOX + n0 + n4 * 4] = o;
        }
    } else {
        for (int i = tid; i < nrem * (NCLS / 4); i += 256) {
            float4 v = src[i];
            int nl = i / 20, c4 = i - nl * 20;
            float4 o;
            o.x = (v.x > SCORE_THR) ? v.x : NEGV;
            o.y = (v.y > SCORE_THR) ? v.y : NEGV;
            o.z = (v.z > SCORE_THR) ? v.z : NEGV;
            o.w = (v.w > SCORE_THR) ? v.w : NEGV;
            *(float4*)&tile[nl][c4 * 4] = o;
        }
        __syncthreads();
        for (int j = tid; j < (nrem / 4) * NCLS; j += 256) {
            int n4 = j / NCLS, c = j - n4 * NCLS;
            float4 o;
            o.x = tile[n4 * 4 + 0][c];
            o.y = tile[n4 * 4 + 1][c];
            o.z = tile[n4 * 4 + 2][c];
            o.w = tile[n4 * 4 + 3][c];
            *(float4*)&st[((size_t)b * NCLS + c) * NBOX + n0 + n4 * 4] = o;
        }
    }
}

// One block per (b,c). Scores live in REGISTERS (val[VPT], all static indexing).
// Thread t owns global indices n = 1024*a + 4*t + q  (a=0..9, q=0..3),
// i.e. val[a*4+q]; within-thread val order is ascending global index.
__global__ __launch_bounds__(256) void nms_extract(
    const float* __restrict__ st,       // (B*C, N) thresholded, or nullptr
    const float* __restrict__ scores,   // raw (B,N,C) fallback
    const float* __restrict__ boxes,    // (B,N,4)
    float* __restrict__ ws_msc,
    float4* __restrict__ ws_box,
    int use_t)
{
    __shared__ float red_val[4];
    __shared__ int   red_idx[4];
    __shared__ float bcast_val[1];
    __shared__ int   bcast_idx[1];
    __shared__ float4 karr[MAXT];
    __shared__ float  karea[MAXT];

    const int bc  = blockIdx.x;
    const int b   = bc / NCLS;
    const int tid = threadIdx.x;
    const float4* box_base = (const float4*)(boxes + (size_t)b * NBOX * 4);

    float val[VPT];
    int   gidx[VPT];   // global index of val[j] (compile-time affine, cheap)

    if (use_t) {
        const float4* row = (const float4*)(st + (size_t)bc * NBOX);
        #pragma unroll
        for (int a = 0; a < 10; ++a) {
            int n = a * 1024 + 4 * tid;           // float4-aligned
            float4 v;
            if (n + 3 < NBOX) v = row[n >> 2];
            else v = make_float4(NEGV, NEGV, NEGV, NEGV);
            val[a * 4 + 0] = v.x; val[a * 4 + 1] = v.y;
            val[a * 4 + 2] = v.z; val[a * 4 + 3] = v.w;
            gidx[a * 4 + 0] = n;     gidx[a * 4 + 1] = n + 1;
            gidx[a * 4 + 2] = n + 2; gidx[a * 4 + 3] = n + 3;
        }
    } else {
        const int c = bc - b * NCLS;
        const float* base = scores + (size_t)b * NBOX * NCLS + c;
        #pragma unroll
        for (int a = 0; a < 10; ++a) {
            #pragma unroll
            for (int q = 0; q < 4; ++q) {
                int n = a * 1024 + 4 * tid + q;
                float v = (n < NBOX) ? base[(size_t)n * NCLS] : NEGV;
                val[a * 4 + q] = (v > SCORE_THR) ? v : NEGV;
                gidx[a * 4 + q] = n;
            }
        }
    }

    // per-thread segment argmax (ascending -> first max)
    float mv = NEGV; int mi = 4 * tid;
    #pragma unroll
    for (int j = 0; j < VPT; ++j) {
        if (val[j] > mv) { mv = val[j]; mi = gidx[j]; }
    }

    int kept = 0;
    for (;;) {
        float bv = mv; int bi = mi;
        block_argmax(bv, bi, red_val, red_idx, bcast_val, bcast_idx, tid);
        if (!(bv > SCORE_THR)) break;

        const float4 cb = box_base[bi];     // uniform addr -> broadcast load
        const float carea = __fmul_rn(__fsub_rn(cb.z, cb.x), __fsub_rn(cb.w, cb.y));

        // IoU vs previously-kept (LDS broadcast reads), per-op IEEE rounding
        bool sup = false;
        #pragma unroll
        for (int j = 0; j < MAXT; ++j) {
            if (j < kept) {
                float4 kb = karr[j];
                float ih = fmaxf(__fsub_rn(fminf(kb.z, cb.z), fmaxf(kb.x, cb.x)), 0.0f);
                float iw = fmaxf(__fsub_rn(fminf(kb.w, cb.w), fmaxf(kb.y, cb.y)), 0.0f);
                float inter = __fmul_rn(ih, iw);
                float uni   = __fsub_rn(__fadd_rn(karea[j], carea), inter);
                float iou   = __fdiv_rn(inter, fmaxf(uni, 1e-9f));
                if (iou > IOU_THR) sup = true;
            }
        }

        if (!sup) {
            if (tid == 0) {
                int o = bc * KSEL + kept;
                ws_msc[o] = bv;
                ws_box[o] = cb;
                karr[kept]  = cb;        // visible to all after next round's barrier
                karea[kept] = carea;
            }
            kept++;
        }

        // owner removes the candidate from its registers and rescans (unrolled)
        if (((bi >> 2) & 255) == tid) {
            float nmv = NEGV; int nmi = 4 * tid;
            #pragma unroll
            for (int j = 0; j < VPT; ++j) {
                if (gidx[j] == bi) val[j] = NEGV;
                if (val[j] > nmv) { nmv = val[j]; nmi = gidx[j]; }
            }
            mv = nmv; mi = nmi;
        }
        if (kept == MAXT) break;
    }

    if (tid == 0) {
        for (int k = kept; k < MAXT; ++k) {
            int o = bc * KSEL + k;
            ws_msc[o] = NEGV;
            ws_box[o] = make_float4(0.f, 0.f, 0.f, 0.f);
        }
    }
}

// One block per batch: stable top-MAXT over C*K masked scores, write outputs.
__global__ __launch_bounds__(256) void topk_combine(
    const float* __restrict__ ws_msc,
    const float4* __restrict__ ws_box,
    float* __restrict__ out)
{
    __shared__ float v[NCLS * KSEL];
    __shared__ float red_val[4];
    __shared__ int   red_idx[4];
    __shared__ float bcast_val[1];
    __shared__ int   bcast_idx[1];
    __shared__ int   sel_i[MAXT];
    __shared__ float sel_v[MAXT];

    const int b = blockIdx.x;
    const int tid = threadIdx.x;

    for (int i = tid; i < NCLS * KSEL; i += 256)
        v[i] = ws_msc[b * NCLS * KSEL + i];
    __syncthreads();

    for (int t = 0; t < MAXT; ++t) {
        float best = -INFINITY;
        int   bidx = 0x7fffffff;
        for (int i = tid; i < NCLS * KSEL; i += 256) {
            float x = v[i];
            if (x > best || (x == best && i < bidx)) { best = x; bidx = i; }
        }
        block_argmax(best, bidx, red_val, red_idx, bcast_val, bcast_idx, tid);
        if (tid == 0) {
            sel_i[t] = bidx;
            sel_v[t] = best;
            v[bidx] = -INFINITY;
        }
        __syncthreads();
    }

    const int OFF_SC = BATCH * MAXT * 4;
    const int OFF_CL = OFF_SC + BATCH * MAXT;
    const int OFF_VD = OFF_CL + BATCH * MAXT;

    if (tid < MAXT) {
        const int t = tid;
        const int idx = sel_i[t];
        const float val = sel_v[t];
        const bool valid = val > SCORE_THR;
        float4 bx = ws_box[b * NCLS * KSEL + idx];
        float* ob = out + ((size_t)b * MAXT + t) * 4;
        ob[0] = valid ? fminf(fmaxf(bx.x, 0.0f), 1.0f) : 0.0f;
        ob[1] = valid ? fminf(fmaxf(bx.y, 0.0f), 1.0f) : 0.0f;
        ob[2] = valid ? fminf(fmaxf(bx.z, 0.0f), 1.0f) : 0.0f;
        ob[3] = valid ? fminf(fmaxf(bx.w, 0.0f), 1.0f) : 0.0f;
        out[OFF_SC + b * MAXT + t] = valid ? val : 0.0f;
        out[OFF_CL + b * MAXT + t] = valid ? (float)(idx >> 3) : 0.0f;
    }
    if (tid == 0) {
        int cnt = 0;
        #pragma unroll
        for (int t = 0; t < MAXT; ++t) cnt += (sel_v[t] > SCORE_THR) ? 1 : 0;
        out[OFF_VD + b] = (float)cnt;
    }
}

extern "C" void kernel_launch(void* const* d_in, const int* in_sizes, int n_in,
                              void* d_out, int out_size, void* d_ws, size_t ws_size,
                              hipStream_t stream) {
    const float* boxes  = (const float*)d_in[0];   // (B, N, 1, 4)
    const float* scores = (const float*)d_in[1];   // (B, N, C)
    float* out = (float*)d_out;

    const size_t t_bytes   = (size_t)BATCH * NCLS * NBOX * sizeof(float); // 25.6 MB
    const size_t msc_bytes = (size_t)BATCH * NCLS * KSEL * sizeof(float);
    const size_t box_bytes = (size_t)BATCH * NCLS * KSEL * sizeof(float4);

    int use_t = (ws_size >= t_bytes + msc_bytes + box_bytes) ? 1 : 0;

    float* st; float* ws_msc; float4* ws_box;
    if (use_t) {
        st     = (float*)d_ws;
        ws_msc = (float*)((char*)d_ws + t_bytes);
        ws_box = (float4*)((char*)d_ws + t_bytes + msc_bytes);
    } else {
        st     = nullptr;
        ws_msc = (float*)d_ws;
        ws_box = (float4*)((char*)d_ws + msc_bytes);
    }

    if (use_t) {
        dim3 tg((NBOX + TILE_N - 1) / TILE_N, BATCH);
        transpose_scores<<<tg, 256, 0, stream>>>(scores, st);
    }
    nms_extract<<<BATCH * NCLS, 256, 0, stream>>>(st, scores, boxes, ws_msc, ws_box, use_t);
    topk_combine<<<BATCH, 256, 0, stream>>>(ws_msc, ws_box, out);
}

// Round 4
// 52.281 us; speedup vs baseline: 2.7255x; 1.1087x over previous
//
#include <hip/hip_runtime.h>
#include <math.h>

#define BATCH 8
#define NBOX 10000
#define NCLS 80
#define KSEL 8
#define MAXT 8
#define IOU_THR 0.5f
#define SCORE_THR 0.5f
#define NEGV -1000000000.0f
#define VPT 40              // 256 threads * 40 = 10240 >= 10000
#define TILE_N 64

// ---------------------------------------------------------------------------
// Transpose + threshold: (B,N,C) -> (B*C, N). Coalesced on BOTH global sides.
// LDS tile[c][n] (stride 65): load side = float4 global loads + 4 scalar LDS
// writes (banks ~4-way, cheap); store side = scalar LDS reads (2-way = free)
// + float4 global stores where 16 consecutive lanes cover 256 contiguous bytes.
// ---------------------------------------------------------------------------
__global__ __launch_bounds__(256) void transpose_scores(
    const float* __restrict__ scores, float* __restrict__ st)
{
    __shared__ float tile[NCLS][TILE_N + 1];   // 80 x 65 floats = 20.8 KB
    const int b   = blockIdx.y;
    const int n0  = blockIdx.x * TILE_N;
    const int tid = threadIdx.x;
    const int nrem = min(TILE_N, NBOX - n0);   // 64, or 16 for the last block
    const float4* src = (const float4*)(scores + (size_t)b * NBOX * NCLS
                                               + (size_t)n0 * NCLS);
    if (nrem == TILE_N) {
        #pragma unroll
        for (int k = 0; k < 5; ++k) {
            int i = tid + k * 256;             // 1280 float4 = 64 boxes x 20
            float4 v = src[i];
            int nl = i / 20, c4 = i - nl * 20;
            tile[c4 * 4 + 0][nl] = (v.x > SCORE_THR) ? v.x : NEGV;
            tile[c4 * 4 + 1][nl] = (v.y > SCORE_THR) ? v.y : NEGV;
            tile[c4 * 4 + 2][nl] = (v.z > SCORE_THR) ? v.z : NEGV;
            tile[c4 * 4 + 3][nl] = (v.w > SCORE_THR) ? v.w : NEGV;
        }
        __syncthreads();
        #pragma unroll
        for (int k = 0; k < 5; ++k) {
            int j = tid + k * 256;             // 1280 float4 = 80 c x 16 n4
            int c = j >> 4, n4 = j & 15;
            float4 o;
            o.x = tile[c][n4 * 4 + 0];
            o.y = tile[c][n4 * 4 + 1];
            o.z = tile[c][n4 * 4 + 2];
            o.w = tile[c][n4 * 4 + 3];
            *(float4*)&st[((size_t)b * NCLS + c) * NBOX + n0 + n4 * 4] = o;
        }
    } else {
        for (int i = tid; i < nrem * (NCLS / 4); i += 256) {
            float4 v = src[i];
            int nl = i / 20, c4 = i - nl * 20;
            tile[c4 * 4 + 0][nl] = (v.x > SCORE_THR) ? v.x : NEGV;
            tile[c4 * 4 + 1][nl] = (v.y > SCORE_THR) ? v.y : NEGV;
            tile[c4 * 4 + 2][nl] = (v.z > SCORE_THR) ? v.z : NEGV;
            tile[c4 * 4 + 3][nl] = (v.w > SCORE_THR) ? v.w : NEGV;
        }
        __syncthreads();
        const int nq = nrem >> 2;
        for (int j = tid; j < nq * NCLS; j += 256) {
            int c = j / nq, n4 = j - c * nq;
            float4 o;
            o.x = tile[c][n4 * 4 + 0];
            o.y = tile[c][n4 * 4 + 1];
            o.z = tile[c][n4 * 4 + 2];
            o.w = tile[c][n4 * 4 + 3];
            *(float4*)&st[((size_t)b * NCLS + c) * NBOX + n0 + n4 * 4] = o;
        }
    }
}

// ---------------------------------------------------------------------------
// One block per (b,c). Scores in REGISTERS (val[VPT], static indexing only).
// Thread t owns n = 1024*a + 4*t + q  ->  val[a*4+q]; ascending j = ascending n.
// One __syncthreads per extraction round (double-buffered reduction slots).
// ---------------------------------------------------------------------------
__global__ __launch_bounds__(256) void nms_extract(
    const float* __restrict__ st,       // (B*C, N) thresholded, or nullptr
    const float* __restrict__ scores,   // raw (B,N,C) fallback
    const float* __restrict__ boxes,    // (B,N,4)
    float* __restrict__ ws_msc,
    float4* __restrict__ ws_box,
    int use_t)
{
    __shared__ float red_val[2][4];
    __shared__ int   red_idx[2][4];
    __shared__ float4 karr[MAXT];
    __shared__ float  karea[MAXT];

    const int bc  = blockIdx.x;
    const int b   = bc / NCLS;
    const int tid = threadIdx.x;
    const float4* box_base = (const float4*)(boxes + (size_t)b * NBOX * 4);

    float val[VPT];

    if (use_t) {
        const float4* row = (const float4*)(st + (size_t)bc * NBOX);
        #pragma unroll
        for (int a = 0; a < 10; ++a) {
            int n = a * 1024 + 4 * tid;
            float4 v;
            if (n + 3 < NBOX) v = row[(a << 8) + tid];
            else v = make_float4(NEGV, NEGV, NEGV, NEGV);
            val[a * 4 + 0] = v.x; val[a * 4 + 1] = v.y;
            val[a * 4 + 2] = v.z; val[a * 4 + 3] = v.w;
        }
    } else {
        const int c = bc - b * NCLS;
        const float* base = scores + (size_t)b * NBOX * NCLS + c;
        #pragma unroll
        for (int a = 0; a < 10; ++a) {
            #pragma unroll
            for (int q = 0; q < 4; ++q) {
                int n = a * 1024 + 4 * tid + q;
                float v = (n < NBOX) ? base[(size_t)n * NCLS] : NEGV;
                val[a * 4 + q] = (v > SCORE_THR) ? v : NEGV;
            }
        }
    }

    const int tid4 = tid << 2;
    // per-thread argmax (ascending j -> first max; index recomputed inline)
    float mv = NEGV; int mi = tid4;
    #pragma unroll
    for (int j = 0; j < VPT; ++j) {
        int n = ((j >> 2) << 10) + tid4 + (j & 3);
        if (val[j] > mv) { mv = val[j]; mi = n; }
    }

    int kept = 0;
    int p = 0;
    for (;;) {
        // ---- block argmax: wave shfl reduce -> LDS slot -> all-lanes combine
        float bv = mv; int bi = mi;
        #pragma unroll
        for (int off = 32; off > 0; off >>= 1) {
            float ov = __shfl_down(bv, off, 64);
            int   oi = __shfl_down(bi, off, 64);
            if (ov > bv || (ov == bv && oi < bi)) { bv = ov; bi = oi; }
        }
        if ((tid & 63) == 0) { red_val[p][tid >> 6] = bv; red_idx[p][tid >> 6] = bi; }
        __syncthreads();
        bv = red_val[p][0]; bi = red_idx[p][0];
        #pragma unroll
        for (int w = 1; w < 4; ++w) {
            float ov = red_val[p][w]; int oi = red_idx[p][w];
            if (ov > bv || (ov == bv && oi < bi)) { bv = ov; bi = oi; }
        }
        p ^= 1;
        if (!(bv > SCORE_THR)) break;

        const float4 cb = box_base[bi];     // uniform addr -> broadcast load
        const float carea = __fmul_rn(__fsub_rn(cb.z, cb.x), __fsub_rn(cb.w, cb.y));

        // IoU vs kept boxes (broadcast LDS reads), per-op IEEE rounding
        bool sup = false;
        #pragma unroll
        for (int j = 0; j < MAXT; ++j) {
            if (j < kept) {
                float4 kb = karr[j];
                float ih = fmaxf(__fsub_rn(fminf(kb.z, cb.z), fmaxf(kb.x, cb.x)), 0.0f);
                float iw = fmaxf(__fsub_rn(fminf(kb.w, cb.w), fmaxf(kb.y, cb.y)), 0.0f);
                float inter = __fmul_rn(ih, iw);
                float uni   = __fsub_rn(__fadd_rn(karea[j], carea), inter);
                float iou   = __fdiv_rn(inter, fmaxf(uni, 1e-9f));
                if (iou > IOU_THR) sup = true;
            }
        }

        if (!sup) {
            if (tid == 0) {
                int o = bc * KSEL + kept;
                ws_msc[o] = bv;
                ws_box[o] = cb;
                karr[kept]  = cb;        // read next round, after its barrier
                karea[kept] = carea;
            }
            kept++;
        }

        // owner removes candidate from registers and rescans (all static idx)
        if (((bi >> 2) & 255) == tid) {
            const int jt = ((bi >> 10) << 2) | (bi & 3);
            float nmv = NEGV; int nmi = tid4;
            #pragma unroll
            for (int j = 0; j < VPT; ++j) {
                if (j == jt) val[j] = NEGV;
                int n = ((j >> 2) << 10) + tid4 + (j & 3);
                if (val[j] > nmv) { nmv = val[j]; nmi = n; }
            }
            mv = nmv; mi = nmi;
        }
        if (kept == MAXT) break;
    }

    if (tid == 0) {
        for (int k = kept; k < MAXT; ++k) {
            int o = bc * KSEL + k;
            ws_msc[o] = NEGV;
            ws_box[o] = make_float4(0.f, 0.f, 0.f, 0.f);
        }
    }
}

// ---------------------------------------------------------------------------
// One block per batch: register-resident stable top-MAXT over C*K = 640 slots.
// 3 values/thread, 1 barrier/round; outputs written by tid==t per round.
// ---------------------------------------------------------------------------
__global__ __launch_bounds__(256) void topk_combine(
    const float* __restrict__ ws_msc,
    const float4* __restrict__ ws_box,
    float* __restrict__ out)
{
    __shared__ float red_val[2][4];
    __shared__ int   red_idx[2][4];

    const int b = blockIdx.x;
    const int tid = threadIdx.x;
    const float* msc = ws_msc + b * NCLS * KSEL;

    float v0 = (tid       < NCLS * KSEL) ? msc[tid]       : -INFINITY;
    float v1 = (tid + 256 < NCLS * KSEL) ? msc[tid + 256] : -INFINITY;
    float v2 = (tid + 512 < NCLS * KSEL) ? msc[tid + 512] : -INFINITY;

    const int OFF_SC = BATCH * MAXT * 4;
    const int OFF_CL = OFF_SC + BATCH * MAXT;
    const int OFF_VD = OFF_CL + BATCH * MAXT;

    int cnt = 0;
    int p = 0;
    #pragma unroll
    for (int t = 0; t < MAXT; ++t) {
        float bv = v0; int bi = tid;
        if (v1 > bv) { bv = v1; bi = tid + 256; }   // ascending i -> first max
        if (v2 > bv) { bv = v2; bi = tid + 512; }
        #pragma unroll
        for (int off = 32; off > 0; off >>= 1) {
            float ov = __shfl_down(bv, off, 64);
            int   oi = __shfl_down(bi, off, 64);
            if (ov > bv || (ov == bv && oi < bi)) { bv = ov; bi = oi; }
        }
        if ((tid & 63) == 0) { red_val[p][tid >> 6] = bv; red_idx[p][tid >> 6] = bi; }
        __syncthreads();
        bv = red_val[p][0]; bi = red_idx[p][0];
        #pragma unroll
        for (int w = 1; w < 4; ++w) {
            float ov = red_val[p][w]; int oi = red_idx[p][w];
            if (ov > bv || (ov == bv && oi < bi)) { bv = ov; bi = oi; }
        }
        p ^= 1;

        const bool valid = bv > SCORE_THR;
        cnt += valid ? 1 : 0;
        if (tid == t) {
            float4 bx = ws_box[b * NCLS * KSEL + bi];
            float* ob = out + ((size_t)b * MAXT + t) * 4;
            ob[0] = valid ? fminf(fmaxf(bx.x, 0.0f), 1.0f) : 0.0f;
            ob[1] = valid ? fminf(fmaxf(bx.y, 0.0f), 1.0f) : 0.0f;
            ob[2] = valid ? fminf(fmaxf(bx.z, 0.0f), 1.0f) : 0.0f;
            ob[3] = valid ? fminf(fmaxf(bx.w, 0.0f), 1.0f) : 0.0f;
            out[OFF_SC + b * MAXT + t] = valid ? bv : 0.0f;
            out[OFF_CL + b * MAXT + t] = valid ? (float)(bi >> 3) : 0.0f;
        }
        // removal (registers; all threads know bi)
        if (tid == (bi & 255)) {
            int w = bi >> 8;
            if (w == 0) v0 = -INFINITY;
            else if (w == 1) v1 = -INFINITY;
            else v2 = -INFINITY;
        }
    }
    if (tid == 0) out[OFF_VD + b] = (float)cnt;
}

extern "C" void kernel_launch(void* const* d_in, const int* in_sizes, int n_in,
                              void* d_out, int out_size, void* d_ws, size_t ws_size,
                              hipStream_t stream) {
    const float* boxes  = (const float*)d_in[0];   // (B, N, 1, 4)
    const float* scores = (const float*)d_in[1];   // (B, N, C)
    float* out = (float*)d_out;

    const size_t t_bytes   = (size_t)BATCH * NCLS * NBOX * sizeof(float); // 25.6 MB
    const size_t msc_bytes = (size_t)BATCH * NCLS * KSEL * sizeof(float);
    const size_t box_bytes = (size_t)BATCH * NCLS * KSEL * sizeof(float4);

    int use_t = (ws_size >= t_bytes + msc_bytes + box_bytes) ? 1 : 0;

    float* st; float* ws_msc; float4* ws_box;
    if (use_t) {
        st     = (float*)d_ws;
        ws_msc = (float*)((char*)d_ws + t_bytes);
        ws_box = (float4*)((char*)d_ws + t_bytes + msc_bytes);
    } else {
        st     = nullptr;
        ws_msc = (float*)d_ws;
        ws_box = (float4*)((char*)d_ws + msc_bytes);
    }

    if (use_t) {
        dim3 tg((NBOX + TILE_N - 1) / TILE_N, BATCH);
        transpose_scores<<<tg, 256, 0, stream>>>(scores, st);
    }
    nms_extract<<<BATCH * NCLS, 256, 0, stream>>>(st, scores, boxes, ws_msc, ws_box, use_t);
    topk_combine<<<BATCH, 256, 0, stream>>>(ws_msc, ws_box, out);
}